// Round 15
// baseline (955.423 us; speedup 1.0000x reference)
//
#include <hip/hip_runtime.h>

// KidneyEdgePredictor — edge-GNN. bf16 h-storage + bf16 MFMA matmuls.
// N=50000 nodes (D=13), E=1,280,000 edges, H=64.
// encoder(27->64) -> 3x conv(scatter-mean by dst/src) -> MLP 64->64->64->32->1.
//
// R14 post-mortem: 898us; top kernel k_enc 155us — WRITE 240MB (76MB over the
// 164MB h-write = fused deg-histogram atomics bouncing across XCDs) and 33%
// VALU (27x64 scalar matmul). R15:
//  (1) histogram -> separate k_deg, XCD-partitioned like k_fill (deg ranges
//      stay in one XCD's L2; no cross-XCD RMW bounce in k_enc).
//  (2) encoder matmul -> MFMA: per-lane feature gather into bf16 LDS row
//      (27 + 5 zero-pad = K=32), A-frags cross-lane from LDS (wave-lockstep),
//      B-frags from wenc with k>=27 zeroed; C-layout store direct to hm.
// Everything else identical to R14. Launch bounds NOT raised (R13 lesson:
// unified VGPR/AGPR file — tighter caps force spills).

#define NN 50000
#define NNP 50048            // m rows padded to 64-tile multiple
#define NE 1280000
#define LDP 72               // u16 pitch for LDS tiles
#define OFFSZ 50016
#define NB 196               // scan blocks: 196*256 = 50176 >= NN
#define NTILES 782           // ceil(NN/64)
#define NPX 6250             // nodes per XCD class (NN/8)

#define WAVES 2
#define EDGE_ITERS 4
#define EDGE_BLOCKS 2500     // 20000 tiles / (2 waves * 4 iters)

typedef unsigned int   u32;
typedef unsigned short u16;
typedef __attribute__((ext_vector_type(8))) short  short8;   // 8 bf16 (4 VGPRs)
typedef __attribute__((ext_vector_type(4))) float  floatx4;  // MFMA acc

#define MFMA16(a, b, c) __builtin_amdgcn_mfma_f32_16x16x32_bf16(a, b, c, 0, 0, 0)

__device__ __forceinline__ float lrelu(float x) { return x >= 0.0f ? x : 0.2f * x; }
__device__ __forceinline__ float bf2f(u16 u) { return __uint_as_float(((u32)u) << 16); }
__device__ __forceinline__ u16 f2bf(float f) {               // RNE
    u32 b = __float_as_uint(f);
    return (u16)((b + 0x7FFFu + ((b >> 16) & 1u)) >> 16);
}
__device__ __forceinline__ u32 f2bf2(float lo, float hi) {   // pack 2 bf16
    return (u32)f2bf(lo) | ((u32)f2bf(hi) << 16);
}

// B-frag: lane holds B[k0..k0+7][n] of a row-major fp32 weight (ld = row stride)
__device__ __forceinline__ short8 bfrag(const float* __restrict__ W, int ld, int n, int k0) {
    short8 b;
#pragma unroll
    for (int j = 0; j < 8; ++j) b[j] = (short)f2bf(W[(k0 + j) * ld + n]);
    return b;
}

// C(64x64) += A(64x64 from bf16 LDS tile) @ B(frags)
__device__ __forceinline__ void mm_tile(const u16* __restrict__ tb,
                                        const short8 wf[2][4],
                                        floatx4 acc[4][4], int c16, int q4) {
#pragma unroll
    for (int mt = 0; mt < 4; ++mt) {
        const short8 a0 = *(const short8*)(tb + (mt * 16 + c16) * LDP + q4 * 8);
        const short8 a1 = *(const short8*)(tb + (mt * 16 + c16) * LDP + 32 + q4 * 8);
#pragma unroll
        for (int nt = 0; nt < 4; ++nt) {
            acc[mt][nt] = MFMA16(a0, wf[0][nt], acc[mt][nt]);
            acc[mt][nt] = MFMA16(a1, wf[1][nt], acc[mt][nt]);
        }
    }
}

// ---------------- XCD-partitioned degree histogram ----------------
__global__ void __launch_bounds__(256)
k_deg(const int* __restrict__ ei, int* __restrict__ deg_in, int* __restrict__ deg_out)
{
    const int cls   = blockIdx.x & 7;
    const int slice = blockIdx.x >> 3;                 // NE/2048 slices
    const int base  = (slice * 256 + threadIdx.x) * 8;
    const int lo = cls * NPX, hi = lo + NPX;
    int s[8], d[8];
#pragma unroll
    for (int k = 0; k < 8; ++k) s[k] = ei[base + k];
#pragma unroll
    for (int k = 0; k < 8; ++k) d[k] = ei[NE + base + k];
#pragma unroll
    for (int k = 0; k < 8; ++k)
        if (s[k] >= lo && s[k] < hi) atomicAdd(&deg_out[s[k]], 1);
#pragma unroll
    for (int k = 0; k < 8; ++k)
        if (d[k] >= lo && d[k] < hi) atomicAdd(&deg_in[d[k]], 1);
}

// ---------------- hierarchical CSR scan ----------------
__global__ void __launch_bounds__(256)
k_bsum(const int* __restrict__ deg_in, const int* __restrict__ deg_out,
       int* __restrict__ bsum)
{
    __shared__ int s[256];
    const int tid = threadIdx.x;
    const int i = blockIdx.x * 256 + tid;
#pragma unroll 1
    for (int pass = 0; pass < 2; ++pass) {
        const int* deg = pass ? deg_out : deg_in;
        s[tid] = (i < NN) ? deg[i] : 0;
        __syncthreads();
        for (int d = 128; d > 0; d >>= 1) {
            if (tid < d) s[tid] += s[tid + d];
            __syncthreads();
        }
        if (tid == 0) bsum[pass * NB + blockIdx.x] = s[0];
        __syncthreads();
    }
}

__global__ void __launch_bounds__(256)
k_bscan(const int* __restrict__ bsum, int* __restrict__ boff)
{
    __shared__ int s[256];
    const int tid = threadIdx.x;
#pragma unroll 1
    for (int pass = 0; pass < 2; ++pass) {
        const int v = (tid < NB) ? bsum[pass * NB + tid] : 0;
        s[tid] = v;
        __syncthreads();
        for (int d = 1; d < 256; d <<= 1) {
            const int t = (tid >= d) ? s[tid - d] : 0;
            __syncthreads();
            s[tid] += t;
            __syncthreads();
        }
        if (tid < NB) boff[pass * NB + tid] = s[tid] - v;   // exclusive
        __syncthreads();
    }
}

// block-local scan + block offset -> off & cur (coalesced)
__global__ void __launch_bounds__(256)
k_bfill(const int* __restrict__ deg_in, const int* __restrict__ deg_out,
        const int* __restrict__ boff,
        int* __restrict__ off_in, int* __restrict__ off_out,
        int* __restrict__ cur_in, int* __restrict__ cur_out)
{
    __shared__ int s[256];
    const int tid = threadIdx.x;
    const int i = blockIdx.x * 256 + tid;
#pragma unroll 1
    for (int pass = 0; pass < 2; ++pass) {
        const int* deg = pass ? deg_out : deg_in;
        int* off = pass ? off_out : off_in;
        int* cur = pass ? cur_out : cur_in;
        const int v = (i < NN) ? deg[i] : 0;
        s[tid] = v;
        __syncthreads();
        for (int d = 1; d < 256; d <<= 1) {
            const int t = (tid >= d) ? s[tid - d] : 0;
            __syncthreads();
            s[tid] += t;
            __syncthreads();
        }
        const int o = boff[pass * NB + blockIdx.x] + s[tid] - v;
        if (i < NN) { off[i] = o; cur[i] = o; }
        if (i == NN - 1) off[NN] = NE;
        __syncthreads();
    }
}

// XCD-partitioned CSR fill (R12 design)
__global__ void __launch_bounds__(256)
k_fill(const int* __restrict__ ei, int* __restrict__ cur_in, int* __restrict__ cur_out,
       int* __restrict__ csr_in, int* __restrict__ csr_out)
{
    const int cls   = blockIdx.x & 7;
    const int slice = blockIdx.x >> 3;
    const int base  = (slice * 256 + threadIdx.x) * 8;
    const int lo = cls * NPX, hi = lo + NPX;
    int s[8], d[8];
#pragma unroll
    for (int k = 0; k < 8; ++k) s[k] = ei[base + k];
#pragma unroll
    for (int k = 0; k < 8; ++k) d[k] = ei[NE + base + k];
#pragma unroll
    for (int k = 0; k < 8; ++k)
        if (s[k] >= lo && s[k] < hi) {
            const int p = atomicAdd(&cur_out[s[k]], 1);
            csr_out[p] = base + k;
        }
#pragma unroll
    for (int k = 0; k < 8; ++k)
        if (d[k] >= lo && d[k] < hi) {
            const int q = atomicAdd(&cur_in[d[k]], 1);
            csr_in[q] = base + k;
        }
}

// ---------------- encoder, MFMA (K=32: 27 features + 5 zero-pad) ----------------
__global__ void __launch_bounds__(128)
k_enc(const float* __restrict__ x, const int* __restrict__ ei,
      const float* __restrict__ raw, const float* __restrict__ wenc,
      const float* __restrict__ benc, u16* __restrict__ hm)
{
    __shared__ alignas(16) u16 tile[WAVES][64 * LDP];
    const int w = threadIdx.x >> 6, lane = threadIdx.x & 63;
    const int c16 = lane & 15, q4 = lane >> 4;

    // B-frags: B[k=q4*8+j][n=nt*16+c16], zero for k>=27
    short8 wf[4];
    float bias[4];
#pragma unroll
    for (int nt = 0; nt < 4; ++nt) {
        short8 b;
#pragma unroll
        for (int j = 0; j < 8; ++j) {
            const int k = q4 * 8 + j;
            b[j] = (short)(k < 27 ? f2bf(wenc[k * 64 + nt * 16 + c16]) : 0);
        }
        wf[nt] = b;
        bias[nt] = benc[nt * 16 + c16];
    }

    for (int it = 0; it < EDGE_ITERS; ++it) {
        const int tileId = (it * EDGE_BLOCKS + blockIdx.x) * WAVES + w;
        const int e0 = tileId * 64;

        const int ms = ei[e0 + lane];
        const int md = ei[NE + e0 + lane];

        // gather features bf16 into MY row (lane-private writes)
        u16* row = tile[w] + lane * LDP;
#pragma unroll
        for (int j = 0; j < 13; ++j) row[j]      = f2bf(x[ms * 13 + j]);
#pragma unroll
        for (int j = 0; j < 13; ++j) row[13 + j] = f2bf(x[md * 13 + j]);
        row[26] = f2bf(raw[e0 + lane]);
#pragma unroll
        for (int j = 27; j < 32; ++j) row[j] = 0;

        // MFMA: A[m=mt*16+c16][k=q4*8+j] from LDS rows (cross-lane, same wave —
        // lockstep + compiler lgkm ordering, no barrier). C-layout -> hm direct.
#pragma unroll
        for (int mt = 0; mt < 4; ++mt) {
            const short8 a = *(const short8*)(tile[w] + (mt * 16 + c16) * LDP + q4 * 8);
            floatx4 acc[4];
#pragma unroll
            for (int nt = 0; nt < 4; ++nt) acc[nt] = (floatx4)(0.0f);
#pragma unroll
            for (int nt = 0; nt < 4; ++nt) acc[nt] = MFMA16(a, wf[nt], acc[nt]);
#pragma unroll
            for (int nt = 0; nt < 4; ++nt)
#pragma unroll
                for (int r = 0; r < 4; ++r) {
                    const int rowi = mt * 16 + q4 * 4 + r;
                    hm[(size_t)(e0 + rowi) * 64 + nt * 16 + c16] =
                        f2bf(lrelu(acc[nt][r] + bias[nt]));
                }
        }
    }
}

// ---------------- per-node mean gather (wave per node, max TLP) ----------------
__global__ void __launch_bounds__(256)
k_mean(const u16* __restrict__ hm,
       const int* __restrict__ off_in, const int* __restrict__ csr_in,
       const int* __restrict__ off_out, const int* __restrict__ csr_out,
       u16* __restrict__ m_in, u16* __restrict__ m_out)
{
    const int w = threadIdx.x >> 6, lane = threadIdx.x & 63;
    const int node = blockIdx.x * 4 + w;               // grid*4 == NN exactly
    const int rg = lane >> 3;                          // row slot in 8-batch
    const int co = (lane & 7) * 8;                     // channel octet base

    for (int pass = 0; pass < 2; ++pass) {
        const int* off = pass ? off_out : off_in;
        const int* csr = pass ? csr_out : csr_in;
        u16* mp        = pass ? m_out : m_in;

        const int b0 = off[node], b1 = off[node + 1];
        float fa[8], fb[8];
#pragma unroll
        for (int c = 0; c < 8; ++c) { fa[c] = 0.f; fb[c] = 0.f; }

        int j = b0;
        for (; j + 16 <= b1; j += 16) {                // 16 rows in flight
            const int ea = csr[j + rg];
            const int eb = csr[j + 8 + rg];
            const short8 va = *(const short8*)(hm + (size_t)ea * 64 + co);
            const short8 vb = *(const short8*)(hm + (size_t)eb * 64 + co);
#pragma unroll
            for (int c = 0; c < 8; ++c) fa[c] += bf2f((u16)va[c]);
#pragma unroll
            for (int c = 0; c < 8; ++c) fb[c] += bf2f((u16)vb[c]);
        }
        for (; j < b1; j += 8) {                       // tail, predicated
            const int jj = j + rg;
            const int idx = jj < b1 ? jj : b0;         // safe (loop => b0<b1)
            const float fl = jj < b1 ? 1.f : 0.f;
            const int e = csr[idx];
            const short8 v = *(const short8*)(hm + (size_t)e * 64 + co);
#pragma unroll
            for (int c = 0; c < 8; ++c) fa[c] += fl * bf2f((u16)v[c]);
        }
#pragma unroll
        for (int c = 0; c < 8; ++c) fa[c] += fb[c];
#pragma unroll
        for (int d = 8; d < 64; d <<= 1)
#pragma unroll
            for (int c = 0; c < 8; ++c) fa[c] += __shfl_xor(fa[c], d, 64);

        const int deg = b1 - b0;
        const float inv = 1.0f / (float)(deg > 0 ? deg : 1);
        if (lane < 8) {                                // 16B/lane, 128B row
            uint4 p;
            p.x = f2bf2(fa[0] * inv, fa[1] * inv);
            p.y = f2bf2(fa[2] * inv, fa[3] * inv);
            p.z = f2bf2(fa[4] * inv, fa[5] * inv);
            p.w = f2bf2(fa[6] * inv, fa[7] * inv);
            *(uint4*)(mp + (size_t)node * 64 + lane * 8) = p;
        }
    }
}

// ---------------- dense node transform: T = M @ W (MFMA), bf16 T out ----------------
__global__ void __launch_bounds__(256)
k_nodemm(const u16* __restrict__ m_in, const u16* __restrict__ m_out,
         const float* __restrict__ w_in, const float* __restrict__ w_out,
         u16* __restrict__ t_in, u16* __restrict__ t_out)
{
    const int w = threadIdx.x >> 6, lane = threadIdx.x & 63;
    const int c16 = lane & 15, q4 = lane >> 4;
    const int tileId = blockIdx.x * 4 + w;             // 196*4=784 >= NTILES
    if (tileId >= NTILES) return;
    const int n0 = tileId * 64;

    for (int pass = 0; pass < 2; ++pass) {
        const u16* mp   = pass ? m_out : m_in;
        const float* wp = pass ? w_out : w_in;
        u16* tp         = pass ? t_out : t_in;

        short8 wf[2][4];
#pragma unroll
        for (int ks = 0; ks < 2; ++ks)
#pragma unroll
            for (int nt = 0; nt < 4; ++nt)
                wf[ks][nt] = bfrag(wp, 64, nt * 16 + c16, ks * 32 + q4 * 8);

#pragma unroll
        for (int mt = 0; mt < 4; ++mt) {
            const short8* ap = (const short8*)(mp + (size_t)(n0 + mt * 16 + c16) * 64 + q4 * 8);
            const short8 a0 = ap[0];
            const short8 a1 = ap[4];
            floatx4 acc[4];
#pragma unroll
            for (int nt = 0; nt < 4; ++nt) acc[nt] = (floatx4)(0.0f);
#pragma unroll
            for (int nt = 0; nt < 4; ++nt) {
                acc[nt] = MFMA16(a0, wf[0][nt], acc[nt]);
                acc[nt] = MFMA16(a1, wf[1][nt], acc[nt]);
            }
            // C-layout bf16 store: node = n0 + mt*16 + q4*4 + r
#pragma unroll
            for (int nt = 0; nt < 4; ++nt)
#pragma unroll
                for (int r = 0; r < 4; ++r) {
                    const int node = n0 + mt * 16 + q4 * 4 + r;
                    if (node < NN)
                        tp[(size_t)node * 64 + nt * 16 + c16] = f2bf(acc[nt][r]);
                }
        }
    }
}

// ---------------- conv edge update (layers 1,2), MFMA, no LDS tile ----------------
__global__ void __launch_bounds__(128, 4)
k_edge(const float* __restrict__ wself, const float* __restrict__ bself,
       const u16* __restrict__ t_in, const u16* __restrict__ t_out,
       const int* __restrict__ ei, u16* __restrict__ hm)
{
    __shared__ int sidx[WAVES][64], didx[WAVES][64];
    const int w = threadIdx.x >> 6, lane = threadIdx.x & 63;
    const int c16 = lane & 15, q4 = lane >> 4;

    short8 wf[2][4];                                   // Wself bf16 frags, resident
    float bias[4];
#pragma unroll
    for (int ks = 0; ks < 2; ++ks)
#pragma unroll
        for (int nt = 0; nt < 4; ++nt)
            wf[ks][nt] = bfrag(wself, 64, nt * 16 + c16, ks * 32 + q4 * 8);
#pragma unroll
    for (int nt = 0; nt < 4; ++nt) bias[nt] = bself[nt * 16 + c16];

    for (int it = 0; it < EDGE_ITERS; ++it) {
        const int tileId = (it * EDGE_BLOCKS + blockIdx.x) * WAVES + w;
        const int e0 = tileId * 64;
        sidx[w][lane] = ei[e0 + lane];                 // wave-private, lockstep
        didx[w][lane] = ei[NE + e0 + lane];

#pragma unroll
        for (int mt = 0; mt < 4; ++mt) {
            // A-frags for rows mt*16+c16 (disjoint from rows stored below)
            const short8* ap = (const short8*)(hm + (size_t)(e0 + mt * 16 + c16) * 64 + q4 * 8);
            const short8 a0 = ap[0];
            const short8 a1 = ap[4];
            floatx4 acc[4];
#pragma unroll
            for (int nt = 0; nt < 4; ++nt) acc[nt] = (floatx4)(0.0f);
#pragma unroll
            for (int nt = 0; nt < 4; ++nt) {
                acc[nt] = MFMA16(a0, wf[0][nt], acc[nt]);
                acc[nt] = MFMA16(a1, wf[1][nt], acc[nt]);
            }
            // t gathers (bf16) for rows mt*16+q4*4+r (C-layout rows)
            float tv[4][4], uv[4][4];
#pragma unroll
            for (int r = 0; r < 4; ++r) {
                const int s = sidx[w][mt * 16 + q4 * 4 + r];
#pragma unroll
                for (int nt = 0; nt < 4; ++nt)
                    tv[r][nt] = bf2f(t_in[(size_t)s * 64 + nt * 16 + c16]);
            }
#pragma unroll
            for (int r = 0; r < 4; ++r) {
                const int d = didx[w][mt * 16 + q4 * 4 + r];
#pragma unroll
                for (int nt = 0; nt < 4; ++nt)
                    uv[r][nt] = bf2f(t_out[(size_t)d * 64 + nt * 16 + c16]);
            }
#pragma unroll
            for (int nt = 0; nt < 4; ++nt)
#pragma unroll
                for (int r = 0; r < 4; ++r) {
                    const int row = mt * 16 + q4 * 4 + r;
                    const float v = acc[nt][r] + bias[nt] + tv[r][nt] + uv[r][nt];
                    hm[(size_t)(e0 + row) * 64 + nt * 16 + c16] = f2bf(lrelu(v));
                }
        }
    }
}

// ---------------- conv3 + MLP head fused, MFMA ----------------
__global__ void __launch_bounds__(128, 2)
k_edge_mlp(const float* __restrict__ wself, const float* __restrict__ bself,
           const u16* __restrict__ t_in, const u16* __restrict__ t_out,
           const int* __restrict__ ei, const u16* __restrict__ hm,
           const float* __restrict__ w1, const float* __restrict__ b1,
           const float* __restrict__ w2, const float* __restrict__ b2,
           const float* __restrict__ w3, const float* __restrict__ b3,
           const float* __restrict__ w4, const float* __restrict__ b4,
           float* __restrict__ out)
{
    __shared__ alignas(16) u16 tile[WAVES][64 * LDP];
    __shared__ int sidx[WAVES][64], didx[WAVES][64];
    const int w = threadIdx.x >> 6, lane = threadIdx.x & 63;
    const int c16 = lane & 15, q4 = lane >> 4;

    short8 wfS[2][4], wf1[2][4], wf2[2][4], wf3[2][2];
    float bS[4], bv1[4], bv2[4], bv3[2];
#pragma unroll
    for (int ks = 0; ks < 2; ++ks) {
#pragma unroll
        for (int nt = 0; nt < 4; ++nt) {
            wfS[ks][nt] = bfrag(wself, 64, nt * 16 + c16, ks * 32 + q4 * 8);
            wf1[ks][nt] = bfrag(w1,    64, nt * 16 + c16, ks * 32 + q4 * 8);
            wf2[ks][nt] = bfrag(w2,    64, nt * 16 + c16, ks * 32 + q4 * 8);
        }
#pragma unroll
        for (int nt = 0; nt < 2; ++nt)
            wf3[ks][nt] = bfrag(w3, 32, nt * 16 + c16, ks * 32 + q4 * 8);
    }
#pragma unroll
    for (int nt = 0; nt < 4; ++nt) { bS[nt] = bself[nt*16+c16]; bv1[nt] = b1[nt*16+c16]; bv2[nt] = b2[nt*16+c16]; }
#pragma unroll
    for (int nt = 0; nt < 2; ++nt) bv3[nt] = b3[nt * 16 + c16];
    const float w4a = w4[c16], w4b = w4[16 + c16], b4v = b4[0];

    for (int it = 0; it < EDGE_ITERS; ++it) {
        const int tileId = (it * EDGE_BLOCKS + blockIdx.x) * WAVES + w;
        const int e0 = tileId * 64;
        sidx[w][lane] = ei[e0 + lane];
        didx[w][lane] = ei[NE + e0 + lane];

        // conv3: MFMA + direct t-add in C-layout, h3 -> LDS tile (one rounding)
#pragma unroll
        for (int mt = 0; mt < 4; ++mt) {
            const short8* ap = (const short8*)(hm + (size_t)(e0 + mt * 16 + c16) * 64 + q4 * 8);
            const short8 a0 = ap[0];
            const short8 a1 = ap[4];
            floatx4 acc[4];
#pragma unroll
            for (int nt = 0; nt < 4; ++nt) acc[nt] = (floatx4)(0.0f);
#pragma unroll
            for (int nt = 0; nt < 4; ++nt) {
                acc[nt] = MFMA16(a0, wfS[0][nt], acc[nt]);
                acc[nt] = MFMA16(a1, wfS[1][nt], acc[nt]);
            }
            float tv[4][4], uv[4][4];
#pragma unroll
            for (int r = 0; r < 4; ++r) {
                const int s = sidx[w][mt * 16 + q4 * 4 + r];
#pragma unroll
                for (int nt = 0; nt < 4; ++nt)
                    tv[r][nt] = bf2f(t_in[(size_t)s * 64 + nt * 16 + c16]);
            }
#pragma unroll
            for (int r = 0; r < 4; ++r) {
                const int d = didx[w][mt * 16 + q4 * 4 + r];
#pragma unroll
                for (int nt = 0; nt < 4; ++nt)
                    uv[r][nt] = bf2f(t_out[(size_t)d * 64 + nt * 16 + c16]);
            }
#pragma unroll
            for (int nt = 0; nt < 4; ++nt)
#pragma unroll
                for (int r = 0; r < 4; ++r) {
                    const int row = mt * 16 + q4 * 4 + r;
                    const float v = acc[nt][r] + bS[nt] + tv[r][nt] + uv[r][nt];
                    tile[w][row * LDP + nt * 16 + c16] = f2bf(lrelu(v));
                }
        }

        floatx4 acc[4][4];
        // MLP L1 (tile -> tile)
#pragma unroll
        for (int mt = 0; mt < 4; ++mt)
#pragma unroll
            for (int nt = 0; nt < 4; ++nt) acc[mt][nt] = (floatx4)(0.0f);
        mm_tile(tile[w], wf1, acc, c16, q4);
#pragma unroll
        for (int mt = 0; mt < 4; ++mt)
#pragma unroll
            for (int nt = 0; nt < 4; ++nt)
#pragma unroll
                for (int r = 0; r < 4; ++r)
                    tile[w][(mt * 16 + q4 * 4 + r) * LDP + nt * 16 + c16] =
                        f2bf(lrelu(acc[mt][nt][r] + bv1[nt]));

        // MLP L2
#pragma unroll
        for (int mt = 0; mt < 4; ++mt)
#pragma unroll
            for (int nt = 0; nt < 4; ++nt) acc[mt][nt] = (floatx4)(0.0f);
        mm_tile(tile[w], wf2, acc, c16, q4);
#pragma unroll
        for (int mt = 0; mt < 4; ++mt)
#pragma unroll
            for (int nt = 0; nt < 4; ++nt)
#pragma unroll
                for (int r = 0; r < 4; ++r)
                    tile[w][(mt * 16 + q4 * 4 + r) * LDP + nt * 16 + c16] =
                        f2bf(lrelu(acc[mt][nt][r] + bv2[nt]));

        // MLP L3: 64 -> 32 (acc in registers)
        floatx4 a3[4][2];
#pragma unroll
        for (int mt = 0; mt < 4; ++mt)
#pragma unroll
            for (int nt = 0; nt < 2; ++nt) a3[mt][nt] = (floatx4)(0.0f);
#pragma unroll
        for (int mt = 0; mt < 4; ++mt) {
            const short8 a0 = *(const short8*)(tile[w] + (mt * 16 + c16) * LDP + q4 * 8);
            const short8 a1 = *(const short8*)(tile[w] + (mt * 16 + c16) * LDP + 32 + q4 * 8);
#pragma unroll
            for (int nt = 0; nt < 2; ++nt) {
                a3[mt][nt] = MFMA16(a0, wf3[0][nt], a3[mt][nt]);
                a3[mt][nt] = MFMA16(a1, wf3[1][nt], a3[mt][nt]);
            }
        }
        // MLP L4 in registers: butterfly over c16 (no LDS, no bank conflicts)
#pragma unroll
        for (int mt = 0; mt < 4; ++mt)
#pragma unroll
            for (int r = 0; r < 4; ++r) {
                float p = lrelu(a3[mt][0][r] + bv3[0]) * w4a
                        + lrelu(a3[mt][1][r] + bv3[1]) * w4b;
                p += __shfl_xor(p, 1, 64);
                p += __shfl_xor(p, 2, 64);
                p += __shfl_xor(p, 4, 64);
                p += __shfl_xor(p, 8, 64);
                if (c16 == 0) out[e0 + mt * 16 + q4 * 4 + r] = p + b4v;
            }
    }
}

extern "C" void kernel_launch(void* const* d_in, const int* in_sizes, int n_in,
                              void* d_out, int out_size, void* d_ws, size_t ws_size,
                              hipStream_t stream)
{
    const float* x      = (const float*)d_in[0];
    const int*   ei     = (const int*)  d_in[1];
    const float* raw    = (const float*)d_in[2];
    const float* wenc   = (const float*)d_in[3];
    const float* benc   = (const float*)d_in[4];
    const float* wself1 = (const float*)d_in[5];
    const float* bself1 = (const float*)d_in[6];
    const float* win1   = (const float*)d_in[7];
    const float* wout1  = (const float*)d_in[8];
    const float* wself2 = (const float*)d_in[9];
    const float* bself2 = (const float*)d_in[10];
    const float* win2   = (const float*)d_in[11];
    const float* wout2  = (const float*)d_in[12];
    const float* wself3 = (const float*)d_in[13];
    const float* bself3 = (const float*)d_in[14];
    const float* win3   = (const float*)d_in[15];
    const float* wout3  = (const float*)d_in[16];
    const float* w1 = (const float*)d_in[17]; const float* b1 = (const float*)d_in[18];
    const float* w2 = (const float*)d_in[19]; const float* b2 = (const float*)d_in[20];
    const float* w3 = (const float*)d_in[21]; const float* b3 = (const float*)d_in[22];
    const float* w4 = (const float*)d_in[23]; const float* b4 = (const float*)d_in[24];

    // ws: t_in|t_out (bf16) · deg/cur/off/csr/bsum/boff (int) · m_in|m_out (bf16)
    //     · hm (bf16)  ≈ 201 MB total
    u16*   t_in    = (u16*)d_ws;
    u16*   t_out   = t_in + (size_t)NN * 64;
    int*   deg_in  = (int*)(t_out + (size_t)NN * 64);
    int*   deg_out = deg_in + NN;
    int*   cur_in  = deg_out + NN;
    int*   cur_out = cur_in + NN;
    int*   off_in  = cur_out + NN;
    int*   off_out = off_in + OFFSZ;
    int*   csr_in  = off_out + OFFSZ;
    int*   csr_out = csr_in + NE;
    int*   bsum    = csr_out + NE;                     // 2*NB ints (512-pad)
    int*   boff    = bsum + 512;
    u16*   m_in    = (u16*)(boff + 512);               // NNP*64 bf16
    u16*   m_out   = m_in + (size_t)NNP * 64;
    u16*   hm      = m_out + (size_t)NNP * 64;         // 16B-aligned

    hipMemsetAsync(deg_in, 0, (size_t)2 * NN * sizeof(int), stream);

    // XCD-partitioned degree histogram (was fused in k_enc: cross-XCD bounce)
    k_deg<<<8 * (NE / 2048), 256, 0, stream>>>(ei, deg_in, deg_out);

    // encoder (MFMA, no atomics)
    k_enc<<<EDGE_BLOCKS, 128, 0, stream>>>(x, ei, raw, wenc, benc, hm);

    // hierarchical scan + XCD-partitioned CSR fill
    k_bsum <<<NB, 256, 0, stream>>>(deg_in, deg_out, bsum);
    k_bscan<<<1,  256, 0, stream>>>(bsum, boff);
    k_bfill<<<NB, 256, 0, stream>>>(deg_in, deg_out, boff, off_in, off_out, cur_in, cur_out);
    k_fill<<<8 * (NE / 2048), 256, 0, stream>>>(ei, cur_in, cur_out, csr_in, csr_out);

    for (int layer = 0; layer < 3; ++layer) {
        const float* wi = layer == 0 ? win1  : layer == 1 ? win2  : win3;
        const float* wo = layer == 0 ? wout1 : layer == 1 ? wout2 : wout3;
        k_mean<<<NN / 4, 256, 0, stream>>>(hm, off_in, csr_in, off_out, csr_out,
                                           m_in, m_out);
        k_nodemm<<<NB, 256, 0, stream>>>(m_in, m_out, wi, wo, t_in, t_out);
        if (layer == 0)
            k_edge<<<EDGE_BLOCKS, 128, 0, stream>>>(wself1, bself1, t_in, t_out, ei, hm);
        else if (layer == 1)
            k_edge<<<EDGE_BLOCKS, 128, 0, stream>>>(wself2, bself2, t_in, t_out, ei, hm);
        else
            k_edge_mlp<<<EDGE_BLOCKS, 128, 0, stream>>>(wself3, bself3, t_in, t_out, ei, hm,
                                                        w1, b1, w2, b2, w3, b3, w4, b4,
                                                        (float*)d_out);
    }
}

// Round 16
// 895.376 us; speedup vs baseline: 1.0671x; 1.0671x over previous
//
#include <hip/hip_runtime.h>

// KidneyEdgePredictor — edge-GNN. bf16 h-storage + bf16 MFMA matmuls.
// N=50000 nodes (D=13), E=1,280,000 edges, H=64.
// encoder(27->64) -> 3x conv(scatter-mean by dst/src) -> MLP 64->64->64->32->1.
//
// R15 post-mortem: separate k_deg REGRESSED (+57us: 8x ei re-read, 7/8 wasted
// loads; R14's fused histogram atomics were hidden under k_enc compute).
// R16 hybrid = R14 structure + R15's MFMA encoder matmul:
//   k_enc: fused deg histogram (atomics overlap compute) + bf16 feature
//   gather -> K=32 MFMA -> C-layout store to hm. No k_deg.
// Everything else identical to R14 (the 898us best).

#define NN 50000
#define NNP 50048            // m rows padded to 64-tile multiple
#define NE 1280000
#define LDP 72               // u16 pitch for LDS tiles
#define OFFSZ 50016
#define NB 196               // scan blocks: 196*256 = 50176 >= NN
#define NTILES 782           // ceil(NN/64)
#define NPX 6250             // nodes per XCD class (NN/8)

#define WAVES 2
#define EDGE_ITERS 4
#define EDGE_BLOCKS 2500     // 20000 tiles / (2 waves * 4 iters)

typedef unsigned int   u32;
typedef unsigned short u16;
typedef __attribute__((ext_vector_type(8))) short  short8;   // 8 bf16 (4 VGPRs)
typedef __attribute__((ext_vector_type(4))) float  floatx4;  // MFMA acc

#define MFMA16(a, b, c) __builtin_amdgcn_mfma_f32_16x16x32_bf16(a, b, c, 0, 0, 0)

__device__ __forceinline__ float lrelu(float x) { return x >= 0.0f ? x : 0.2f * x; }
__device__ __forceinline__ float bf2f(u16 u) { return __uint_as_float(((u32)u) << 16); }
__device__ __forceinline__ u16 f2bf(float f) {               // RNE
    u32 b = __float_as_uint(f);
    return (u16)((b + 0x7FFFu + ((b >> 16) & 1u)) >> 16);
}
__device__ __forceinline__ u32 f2bf2(float lo, float hi) {   // pack 2 bf16
    return (u32)f2bf(lo) | ((u32)f2bf(hi) << 16);
}

// B-frag: lane holds B[k0..k0+7][n] of a row-major fp32 weight (ld = row stride)
__device__ __forceinline__ short8 bfrag(const float* __restrict__ W, int ld, int n, int k0) {
    short8 b;
#pragma unroll
    for (int j = 0; j < 8; ++j) b[j] = (short)f2bf(W[(k0 + j) * ld + n]);
    return b;
}

// C(64x64) += A(64x64 from bf16 LDS tile) @ B(frags)
__device__ __forceinline__ void mm_tile(const u16* __restrict__ tb,
                                        const short8 wf[2][4],
                                        floatx4 acc[4][4], int c16, int q4) {
#pragma unroll
    for (int mt = 0; mt < 4; ++mt) {
        const short8 a0 = *(const short8*)(tb + (mt * 16 + c16) * LDP + q4 * 8);
        const short8 a1 = *(const short8*)(tb + (mt * 16 + c16) * LDP + 32 + q4 * 8);
#pragma unroll
        for (int nt = 0; nt < 4; ++nt) {
            acc[mt][nt] = MFMA16(a0, wf[0][nt], acc[mt][nt]);
            acc[mt][nt] = MFMA16(a1, wf[1][nt], acc[mt][nt]);
        }
    }
}

// ---------------- hierarchical CSR scan ----------------
__global__ void __launch_bounds__(256)
k_bsum(const int* __restrict__ deg_in, const int* __restrict__ deg_out,
       int* __restrict__ bsum)
{
    __shared__ int s[256];
    const int tid = threadIdx.x;
    const int i = blockIdx.x * 256 + tid;
#pragma unroll 1
    for (int pass = 0; pass < 2; ++pass) {
        const int* deg = pass ? deg_out : deg_in;
        s[tid] = (i < NN) ? deg[i] : 0;
        __syncthreads();
        for (int d = 128; d > 0; d >>= 1) {
            if (tid < d) s[tid] += s[tid + d];
            __syncthreads();
        }
        if (tid == 0) bsum[pass * NB + blockIdx.x] = s[0];
        __syncthreads();
    }
}

__global__ void __launch_bounds__(256)
k_bscan(const int* __restrict__ bsum, int* __restrict__ boff)
{
    __shared__ int s[256];
    const int tid = threadIdx.x;
#pragma unroll 1
    for (int pass = 0; pass < 2; ++pass) {
        const int v = (tid < NB) ? bsum[pass * NB + tid] : 0;
        s[tid] = v;
        __syncthreads();
        for (int d = 1; d < 256; d <<= 1) {
            const int t = (tid >= d) ? s[tid - d] : 0;
            __syncthreads();
            s[tid] += t;
            __syncthreads();
        }
        if (tid < NB) boff[pass * NB + tid] = s[tid] - v;   // exclusive
        __syncthreads();
    }
}

// block-local scan + block offset -> off & cur (coalesced)
__global__ void __launch_bounds__(256)
k_bfill(const int* __restrict__ deg_in, const int* __restrict__ deg_out,
        const int* __restrict__ boff,
        int* __restrict__ off_in, int* __restrict__ off_out,
        int* __restrict__ cur_in, int* __restrict__ cur_out)
{
    __shared__ int s[256];
    const int tid = threadIdx.x;
    const int i = blockIdx.x * 256 + tid;
#pragma unroll 1
    for (int pass = 0; pass < 2; ++pass) {
        const int* deg = pass ? deg_out : deg_in;
        int* off = pass ? off_out : off_in;
        int* cur = pass ? cur_out : cur_in;
        const int v = (i < NN) ? deg[i] : 0;
        s[tid] = v;
        __syncthreads();
        for (int d = 1; d < 256; d <<= 1) {
            const int t = (tid >= d) ? s[tid - d] : 0;
            __syncthreads();
            s[tid] += t;
            __syncthreads();
        }
        const int o = boff[pass * NB + blockIdx.x] + s[tid] - v;
        if (i < NN) { off[i] = o; cur[i] = o; }
        if (i == NN - 1) off[NN] = NE;
        __syncthreads();
    }
}

// XCD-partitioned CSR fill (R12 design)
__global__ void __launch_bounds__(256)
k_fill(const int* __restrict__ ei, int* __restrict__ cur_in, int* __restrict__ cur_out,
       int* __restrict__ csr_in, int* __restrict__ csr_out)
{
    const int cls   = blockIdx.x & 7;
    const int slice = blockIdx.x >> 3;
    const int base  = (slice * 256 + threadIdx.x) * 8;
    const int lo = cls * NPX, hi = lo + NPX;
    int s[8], d[8];
#pragma unroll
    for (int k = 0; k < 8; ++k) s[k] = ei[base + k];
#pragma unroll
    for (int k = 0; k < 8; ++k) d[k] = ei[NE + base + k];
#pragma unroll
    for (int k = 0; k < 8; ++k)
        if (s[k] >= lo && s[k] < hi) {
            const int p = atomicAdd(&cur_out[s[k]], 1);
            csr_out[p] = base + k;
        }
#pragma unroll
    for (int k = 0; k < 8; ++k)
        if (d[k] >= lo && d[k] < hi) {
            const int q = atomicAdd(&cur_in[d[k]], 1);
            csr_in[q] = base + k;
        }
}

// ---------------- encoder: fused histogram + MFMA (K=32: 27 feat + 5 pad) ----------------
__global__ void __launch_bounds__(128)
k_enc(const float* __restrict__ x, const int* __restrict__ ei,
      const float* __restrict__ raw, const float* __restrict__ wenc,
      const float* __restrict__ benc, u16* __restrict__ hm,
      int* __restrict__ deg_in, int* __restrict__ deg_out)
{
    __shared__ alignas(16) u16 tile[WAVES][64 * LDP];
    const int w = threadIdx.x >> 6, lane = threadIdx.x & 63;
    const int c16 = lane & 15, q4 = lane >> 4;

    // B-frags: B[k=q4*8+j][n=nt*16+c16], zero for k>=27
    short8 wf[4];
    float bias[4];
#pragma unroll
    for (int nt = 0; nt < 4; ++nt) {
        short8 b;
#pragma unroll
        for (int j = 0; j < 8; ++j) {
            const int k = q4 * 8 + j;
            b[j] = (short)(k < 27 ? f2bf(wenc[k * 64 + nt * 16 + c16]) : 0);
        }
        wf[nt] = b;
        bias[nt] = benc[nt * 16 + c16];
    }

    for (int it = 0; it < EDGE_ITERS; ++it) {
        const int tileId = (it * EDGE_BLOCKS + blockIdx.x) * WAVES + w;
        const int e0 = tileId * 64;

        const int ms = ei[e0 + lane];
        const int md = ei[NE + e0 + lane];
        atomicAdd(&deg_out[ms], 1);                    // fused histogram (R14:
        atomicAdd(&deg_in[md], 1);                     // overlaps compute)

        // gather features bf16 into MY row (lane-private writes)
        u16* row = tile[w] + lane * LDP;
#pragma unroll
        for (int j = 0; j < 13; ++j) row[j]      = f2bf(x[ms * 13 + j]);
#pragma unroll
        for (int j = 0; j < 13; ++j) row[13 + j] = f2bf(x[md * 13 + j]);
        row[26] = f2bf(raw[e0 + lane]);
#pragma unroll
        for (int j = 27; j < 32; ++j) row[j] = 0;

        // MFMA: A[m=mt*16+c16][k=q4*8+j] from LDS rows (cross-lane, same wave —
        // lockstep + compiler lgkm ordering, no barrier). C-layout -> hm direct.
#pragma unroll
        for (int mt = 0; mt < 4; ++mt) {
            const short8 a = *(const short8*)(tile[w] + (mt * 16 + c16) * LDP + q4 * 8);
            floatx4 acc[4];
#pragma unroll
            for (int nt = 0; nt < 4; ++nt) acc[nt] = (floatx4)(0.0f);
#pragma unroll
            for (int nt = 0; nt < 4; ++nt) acc[nt] = MFMA16(a, wf[nt], acc[nt]);
#pragma unroll
            for (int nt = 0; nt < 4; ++nt)
#pragma unroll
                for (int r = 0; r < 4; ++r) {
                    const int rowi = mt * 16 + q4 * 4 + r;
                    hm[(size_t)(e0 + rowi) * 64 + nt * 16 + c16] =
                        f2bf(lrelu(acc[nt][r] + bias[nt]));
                }
        }
    }
}

// ---------------- per-node mean gather (wave per node, max TLP) ----------------
__global__ void __launch_bounds__(256)
k_mean(const u16* __restrict__ hm,
       const int* __restrict__ off_in, const int* __restrict__ csr_in,
       const int* __restrict__ off_out, const int* __restrict__ csr_out,
       u16* __restrict__ m_in, u16* __restrict__ m_out)
{
    const int w = threadIdx.x >> 6, lane = threadIdx.x & 63;
    const int node = blockIdx.x * 4 + w;               // grid*4 == NN exactly
    const int rg = lane >> 3;                          // row slot in 8-batch
    const int co = (lane & 7) * 8;                     // channel octet base

    for (int pass = 0; pass < 2; ++pass) {
        const int* off = pass ? off_out : off_in;
        const int* csr = pass ? csr_out : csr_in;
        u16* mp        = pass ? m_out : m_in;

        const int b0 = off[node], b1 = off[node + 1];
        float fa[8], fb[8];
#pragma unroll
        for (int c = 0; c < 8; ++c) { fa[c] = 0.f; fb[c] = 0.f; }

        int j = b0;
        for (; j + 16 <= b1; j += 16) {                // 16 rows in flight
            const int ea = csr[j + rg];
            const int eb = csr[j + 8 + rg];
            const short8 va = *(const short8*)(hm + (size_t)ea * 64 + co);
            const short8 vb = *(const short8*)(hm + (size_t)eb * 64 + co);
#pragma unroll
            for (int c = 0; c < 8; ++c) fa[c] += bf2f((u16)va[c]);
#pragma unroll
            for (int c = 0; c < 8; ++c) fb[c] += bf2f((u16)vb[c]);
        }
        for (; j < b1; j += 8) {                       // tail, predicated
            const int jj = j + rg;
            const int idx = jj < b1 ? jj : b0;         // safe (loop => b0<b1)
            const float fl = jj < b1 ? 1.f : 0.f;
            const int e = csr[idx];
            const short8 v = *(const short8*)(hm + (size_t)e * 64 + co);
#pragma unroll
            for (int c = 0; c < 8; ++c) fa[c] += fl * bf2f((u16)v[c]);
        }
#pragma unroll
        for (int c = 0; c < 8; ++c) fa[c] += fb[c];
#pragma unroll
        for (int d = 8; d < 64; d <<= 1)
#pragma unroll
            for (int c = 0; c < 8; ++c) fa[c] += __shfl_xor(fa[c], d, 64);

        const int deg = b1 - b0;
        const float inv = 1.0f / (float)(deg > 0 ? deg : 1);
        if (lane < 8) {                                // 16B/lane, 128B row
            uint4 p;
            p.x = f2bf2(fa[0] * inv, fa[1] * inv);
            p.y = f2bf2(fa[2] * inv, fa[3] * inv);
            p.z = f2bf2(fa[4] * inv, fa[5] * inv);
            p.w = f2bf2(fa[6] * inv, fa[7] * inv);
            *(uint4*)(mp + (size_t)node * 64 + lane * 8) = p;
        }
    }
}

// ---------------- dense node transform: T = M @ W (MFMA), bf16 T out ----------------
__global__ void __launch_bounds__(256)
k_nodemm(const u16* __restrict__ m_in, const u16* __restrict__ m_out,
         const float* __restrict__ w_in, const float* __restrict__ w_out,
         u16* __restrict__ t_in, u16* __restrict__ t_out)
{
    const int w = threadIdx.x >> 6, lane = threadIdx.x & 63;
    const int c16 = lane & 15, q4 = lane >> 4;
    const int tileId = blockIdx.x * 4 + w;             // 196*4=784 >= NTILES
    if (tileId >= NTILES) return;
    const int n0 = tileId * 64;

    for (int pass = 0; pass < 2; ++pass) {
        const u16* mp   = pass ? m_out : m_in;
        const float* wp = pass ? w_out : w_in;
        u16* tp         = pass ? t_out : t_in;

        short8 wf[2][4];
#pragma unroll
        for (int ks = 0; ks < 2; ++ks)
#pragma unroll
            for (int nt = 0; nt < 4; ++nt)
                wf[ks][nt] = bfrag(wp, 64, nt * 16 + c16, ks * 32 + q4 * 8);

#pragma unroll
        for (int mt = 0; mt < 4; ++mt) {
            const short8* ap = (const short8*)(mp + (size_t)(n0 + mt * 16 + c16) * 64 + q4 * 8);
            const short8 a0 = ap[0];
            const short8 a1 = ap[4];
            floatx4 acc[4];
#pragma unroll
            for (int nt = 0; nt < 4; ++nt) acc[nt] = (floatx4)(0.0f);
#pragma unroll
            for (int nt = 0; nt < 4; ++nt) {
                acc[nt] = MFMA16(a0, wf[0][nt], acc[nt]);
                acc[nt] = MFMA16(a1, wf[1][nt], acc[nt]);
            }
            // C-layout bf16 store: node = n0 + mt*16 + q4*4 + r
#pragma unroll
            for (int nt = 0; nt < 4; ++nt)
#pragma unroll
                for (int r = 0; r < 4; ++r) {
                    const int node = n0 + mt * 16 + q4 * 4 + r;
                    if (node < NN)
                        tp[(size_t)node * 64 + nt * 16 + c16] = f2bf(acc[nt][r]);
                }
        }
    }
}

// ---------------- conv edge update (layers 1,2), MFMA, no LDS tile ----------------
__global__ void __launch_bounds__(128, 4)
k_edge(const float* __restrict__ wself, const float* __restrict__ bself,
       const u16* __restrict__ t_in, const u16* __restrict__ t_out,
       const int* __restrict__ ei, u16* __restrict__ hm)
{
    __shared__ int sidx[WAVES][64], didx[WAVES][64];
    const int w = threadIdx.x >> 6, lane = threadIdx.x & 63;
    const int c16 = lane & 15, q4 = lane >> 4;

    short8 wf[2][4];                                   // Wself bf16 frags, resident
    float bias[4];
#pragma unroll
    for (int ks = 0; ks < 2; ++ks)
#pragma unroll
        for (int nt = 0; nt < 4; ++nt)
            wf[ks][nt] = bfrag(wself, 64, nt * 16 + c16, ks * 32 + q4 * 8);
#pragma unroll
    for (int nt = 0; nt < 4; ++nt) bias[nt] = bself[nt * 16 + c16];

    for (int it = 0; it < EDGE_ITERS; ++it) {
        const int tileId = (it * EDGE_BLOCKS + blockIdx.x) * WAVES + w;
        const int e0 = tileId * 64;
        sidx[w][lane] = ei[e0 + lane];                 // wave-private, lockstep
        didx[w][lane] = ei[NE + e0 + lane];

#pragma unroll
        for (int mt = 0; mt < 4; ++mt) {
            // A-frags for rows mt*16+c16 (disjoint from rows stored below)
            const short8* ap = (const short8*)(hm + (size_t)(e0 + mt * 16 + c16) * 64 + q4 * 8);
            const short8 a0 = ap[0];
            const short8 a1 = ap[4];
            floatx4 acc[4];
#pragma unroll
            for (int nt = 0; nt < 4; ++nt) acc[nt] = (floatx4)(0.0f);
#pragma unroll
            for (int nt = 0; nt < 4; ++nt) {
                acc[nt] = MFMA16(a0, wf[0][nt], acc[nt]);
                acc[nt] = MFMA16(a1, wf[1][nt], acc[nt]);
            }
            // t gathers (bf16) for rows mt*16+q4*4+r (C-layout rows)
            float tv[4][4], uv[4][4];
#pragma unroll
            for (int r = 0; r < 4; ++r) {
                const int s = sidx[w][mt * 16 + q4 * 4 + r];
#pragma unroll
                for (int nt = 0; nt < 4; ++nt)
                    tv[r][nt] = bf2f(t_in[(size_t)s * 64 + nt * 16 + c16]);
            }
#pragma unroll
            for (int r = 0; r < 4; ++r) {
                const int d = didx[w][mt * 16 + q4 * 4 + r];
#pragma unroll
                for (int nt = 0; nt < 4; ++nt)
                    uv[r][nt] = bf2f(t_out[(size_t)d * 64 + nt * 16 + c16]);
            }
#pragma unroll
            for (int nt = 0; nt < 4; ++nt)
#pragma unroll
                for (int r = 0; r < 4; ++r) {
                    const int row = mt * 16 + q4 * 4 + r;
                    const float v = acc[nt][r] + bias[nt] + tv[r][nt] + uv[r][nt];
                    hm[(size_t)(e0 + row) * 64 + nt * 16 + c16] = f2bf(lrelu(v));
                }
        }
    }
}

// ---------------- conv3 + MLP head fused, MFMA ----------------
__global__ void __launch_bounds__(128, 2)
k_edge_mlp(const float* __restrict__ wself, const float* __restrict__ bself,
           const u16* __restrict__ t_in, const u16* __restrict__ t_out,
           const int* __restrict__ ei, const u16* __restrict__ hm,
           const float* __restrict__ w1, const float* __restrict__ b1,
           const float* __restrict__ w2, const float* __restrict__ b2,
           const float* __restrict__ w3, const float* __restrict__ b3,
           const float* __restrict__ w4, const float* __restrict__ b4,
           float* __restrict__ out)
{
    __shared__ alignas(16) u16 tile[WAVES][64 * LDP];
    __shared__ int sidx[WAVES][64], didx[WAVES][64];
    const int w = threadIdx.x >> 6, lane = threadIdx.x & 63;
    const int c16 = lane & 15, q4 = lane >> 4;

    short8 wfS[2][4], wf1[2][4], wf2[2][4], wf3[2][2];
    float bS[4], bv1[4], bv2[4], bv3[2];
#pragma unroll
    for (int ks = 0; ks < 2; ++ks) {
#pragma unroll
        for (int nt = 0; nt < 4; ++nt) {
            wfS[ks][nt] = bfrag(wself, 64, nt * 16 + c16, ks * 32 + q4 * 8);
            wf1[ks][nt] = bfrag(w1,    64, nt * 16 + c16, ks * 32 + q4 * 8);
            wf2[ks][nt] = bfrag(w2,    64, nt * 16 + c16, ks * 32 + q4 * 8);
        }
#pragma unroll
        for (int nt = 0; nt < 2; ++nt)
            wf3[ks][nt] = bfrag(w3, 32, nt * 16 + c16, ks * 32 + q4 * 8);
    }
#pragma unroll
    for (int nt = 0; nt < 4; ++nt) { bS[nt] = bself[nt*16+c16]; bv1[nt] = b1[nt*16+c16]; bv2[nt] = b2[nt*16+c16]; }
#pragma unroll
    for (int nt = 0; nt < 2; ++nt) bv3[nt] = b3[nt * 16 + c16];
    const float w4a = w4[c16], w4b = w4[16 + c16], b4v = b4[0];

    for (int it = 0; it < EDGE_ITERS; ++it) {
        const int tileId = (it * EDGE_BLOCKS + blockIdx.x) * WAVES + w;
        const int e0 = tileId * 64;
        sidx[w][lane] = ei[e0 + lane];
        didx[w][lane] = ei[NE + e0 + lane];

        // conv3: MFMA + direct t-add in C-layout, h3 -> LDS tile (one rounding)
#pragma unroll
        for (int mt = 0; mt < 4; ++mt) {
            const short8* ap = (const short8*)(hm + (size_t)(e0 + mt * 16 + c16) * 64 + q4 * 8);
            const short8 a0 = ap[0];
            const short8 a1 = ap[4];
            floatx4 acc[4];
#pragma unroll
            for (int nt = 0; nt < 4; ++nt) acc[nt] = (floatx4)(0.0f);
#pragma unroll
            for (int nt = 0; nt < 4; ++nt) {
                acc[nt] = MFMA16(a0, wfS[0][nt], acc[nt]);
                acc[nt] = MFMA16(a1, wfS[1][nt], acc[nt]);
            }
            float tv[4][4], uv[4][4];
#pragma unroll
            for (int r = 0; r < 4; ++r) {
                const int s = sidx[w][mt * 16 + q4 * 4 + r];
#pragma unroll
                for (int nt = 0; nt < 4; ++nt)
                    tv[r][nt] = bf2f(t_in[(size_t)s * 64 + nt * 16 + c16]);
            }
#pragma unroll
            for (int r = 0; r < 4; ++r) {
                const int d = didx[w][mt * 16 + q4 * 4 + r];
#pragma unroll
                for (int nt = 0; nt < 4; ++nt)
                    uv[r][nt] = bf2f(t_out[(size_t)d * 64 + nt * 16 + c16]);
            }
#pragma unroll
            for (int nt = 0; nt < 4; ++nt)
#pragma unroll
                for (int r = 0; r < 4; ++r) {
                    const int row = mt * 16 + q4 * 4 + r;
                    const float v = acc[nt][r] + bS[nt] + tv[r][nt] + uv[r][nt];
                    tile[w][row * LDP + nt * 16 + c16] = f2bf(lrelu(v));
                }
        }

        floatx4 acc[4][4];
        // MLP L1 (tile -> tile)
#pragma unroll
        for (int mt = 0; mt < 4; ++mt)
#pragma unroll
            for (int nt = 0; nt < 4; ++nt) acc[mt][nt] = (floatx4)(0.0f);
        mm_tile(tile[w], wf1, acc, c16, q4);
#pragma unroll
        for (int mt = 0; mt < 4; ++mt)
#pragma unroll
            for (int nt = 0; nt < 4; ++nt)
#pragma unroll
                for (int r = 0; r < 4; ++r)
                    tile[w][(mt * 16 + q4 * 4 + r) * LDP + nt * 16 + c16] =
                        f2bf(lrelu(acc[mt][nt][r] + bv1[nt]));

        // MLP L2
#pragma unroll
        for (int mt = 0; mt < 4; ++mt)
#pragma unroll
            for (int nt = 0; nt < 4; ++nt) acc[mt][nt] = (floatx4)(0.0f);
        mm_tile(tile[w], wf2, acc, c16, q4);
#pragma unroll
        for (int mt = 0; mt < 4; ++mt)
#pragma unroll
            for (int nt = 0; nt < 4; ++nt)
#pragma unroll
                for (int r = 0; r < 4; ++r)
                    tile[w][(mt * 16 + q4 * 4 + r) * LDP + nt * 16 + c16] =
                        f2bf(lrelu(acc[mt][nt][r] + bv2[nt]));

        // MLP L3: 64 -> 32 (acc in registers)
        floatx4 a3[4][2];
#pragma unroll
        for (int mt = 0; mt < 4; ++mt)
#pragma unroll
            for (int nt = 0; nt < 2; ++nt) a3[mt][nt] = (floatx4)(0.0f);
#pragma unroll
        for (int mt = 0; mt < 4; ++mt) {
            const short8 a0 = *(const short8*)(tile[w] + (mt * 16 + c16) * LDP + q4 * 8);
            const short8 a1 = *(const short8*)(tile[w] + (mt * 16 + c16) * LDP + 32 + q4 * 8);
#pragma unroll
            for (int nt = 0; nt < 2; ++nt) {
                a3[mt][nt] = MFMA16(a0, wf3[0][nt], a3[mt][nt]);
                a3[mt][nt] = MFMA16(a1, wf3[1][nt], a3[mt][nt]);
            }
        }
        // MLP L4 in registers: butterfly over c16 (no LDS, no bank conflicts)
#pragma unroll
        for (int mt = 0; mt < 4; ++mt)
#pragma unroll
            for (int r = 0; r < 4; ++r) {
                float p = lrelu(a3[mt][0][r] + bv3[0]) * w4a
                        + lrelu(a3[mt][1][r] + bv3[1]) * w4b;
                p += __shfl_xor(p, 1, 64);
                p += __shfl_xor(p, 2, 64);
                p += __shfl_xor(p, 4, 64);
                p += __shfl_xor(p, 8, 64);
                if (c16 == 0) out[e0 + mt * 16 + q4 * 4 + r] = p + b4v;
            }
    }
}

extern "C" void kernel_launch(void* const* d_in, const int* in_sizes, int n_in,
                              void* d_out, int out_size, void* d_ws, size_t ws_size,
                              hipStream_t stream)
{
    const float* x      = (const float*)d_in[0];
    const int*   ei     = (const int*)  d_in[1];
    const float* raw    = (const float*)d_in[2];
    const float* wenc   = (const float*)d_in[3];
    const float* benc   = (const float*)d_in[4];
    const float* wself1 = (const float*)d_in[5];
    const float* bself1 = (const float*)d_in[6];
    const float* win1   = (const float*)d_in[7];
    const float* wout1  = (const float*)d_in[8];
    const float* wself2 = (const float*)d_in[9];
    const float* bself2 = (const float*)d_in[10];
    const float* win2   = (const float*)d_in[11];
    const float* wout2  = (const float*)d_in[12];
    const float* wself3 = (const float*)d_in[13];
    const float* bself3 = (const float*)d_in[14];
    const float* win3   = (const float*)d_in[15];
    const float* wout3  = (const float*)d_in[16];
    const float* w1 = (const float*)d_in[17]; const float* b1 = (const float*)d_in[18];
    const float* w2 = (const float*)d_in[19]; const float* b2 = (const float*)d_in[20];
    const float* w3 = (const float*)d_in[21]; const float* b3 = (const float*)d_in[22];
    const float* w4 = (const float*)d_in[23]; const float* b4 = (const float*)d_in[24];

    // ws: t_in|t_out (bf16) · deg/cur/off/csr/bsum/boff (int) · m_in|m_out (bf16)
    //     · hm (bf16)  ≈ 201 MB total
    u16*   t_in    = (u16*)d_ws;
    u16*   t_out   = t_in + (size_t)NN * 64;
    int*   deg_in  = (int*)(t_out + (size_t)NN * 64);
    int*   deg_out = deg_in + NN;
    int*   cur_in  = deg_out + NN;
    int*   cur_out = cur_in + NN;
    int*   off_in  = cur_out + NN;
    int*   off_out = off_in + OFFSZ;
    int*   csr_in  = off_out + OFFSZ;
    int*   csr_out = csr_in + NE;
    int*   bsum    = csr_out + NE;                     // 2*NB ints (512-pad)
    int*   boff    = bsum + 512;
    u16*   m_in    = (u16*)(boff + 512);               // NNP*64 bf16
    u16*   m_out   = m_in + (size_t)NNP * 64;
    u16*   hm      = m_out + (size_t)NNP * 64;         // 16B-aligned

    hipMemsetAsync(deg_in, 0, (size_t)2 * NN * sizeof(int), stream);

    // encoder: fused degree histogram + MFMA matmul
    k_enc<<<EDGE_BLOCKS, 128, 0, stream>>>(x, ei, raw, wenc, benc, hm, deg_in, deg_out);

    // hierarchical scan + XCD-partitioned CSR fill
    k_bsum <<<NB, 256, 0, stream>>>(deg_in, deg_out, bsum);
    k_bscan<<<1,  256, 0, stream>>>(bsum, boff);
    k_bfill<<<NB, 256, 0, stream>>>(deg_in, deg_out, boff, off_in, off_out, cur_in, cur_out);
    k_fill<<<8 * (NE / 2048), 256, 0, stream>>>(ei, cur_in, cur_out, csr_in, csr_out);

    for (int layer = 0; layer < 3; ++layer) {
        const float* wi = layer == 0 ? win1  : layer == 1 ? win2  : win3;
        const float* wo = layer == 0 ? wout1 : layer == 1 ? wout2 : wout3;
        k_mean<<<NN / 4, 256, 0, stream>>>(hm, off_in, csr_in, off_out, csr_out,
                                           m_in, m_out);
        k_nodemm<<<NB, 256, 0, stream>>>(m_in, m_out, wi, wo, t_in, t_out);
        if (layer == 0)
            k_edge<<<EDGE_BLOCKS, 128, 0, stream>>>(wself1, bself1, t_in, t_out, ei, hm);
        else if (layer == 1)
            k_edge<<<EDGE_BLOCKS, 128, 0, stream>>>(wself2, bself2, t_in, t_out, ei, hm);
        else
            k_edge_mlp<<<EDGE_BLOCKS, 128, 0, stream>>>(wself3, bself3, t_in, t_out, ei, hm,
                                                        w1, b1, w2, b2, w3, b3, w4, b4,
                                                        (float*)d_out);
    }
}